// Round 4
// baseline (5675.091 us; speedup 1.0000x reference)
//
#include <hip/hip_runtime.h>
#include <stdint.h>
#include <stddef.h>

// ---------- types ----------
typedef __bf16 bf16_8 __attribute__((ext_vector_type(8)));
typedef float  f32x4  __attribute__((ext_vector_type(4)));

__device__ __forceinline__ unsigned short f2bf(float f) {
    unsigned u = __float_as_uint(f);
    unsigned r = (u + 0x7fffu + ((u >> 16) & 1u)) >> 16;   // RTN-even
    return (unsigned short)r;
}
__device__ __forceinline__ float bf2f(unsigned short s) {
    return __uint_as_float(((unsigned)s) << 16);
}

// ---------- GEMM: C (+modes) = A[M,K](f32) * B[K,N](f32) via bf16 MFMA ----------
// 128x128 tile, BK=32, 256 threads (2x2 waves x 4x4 MFMA 16x16x32).
// TERMS=6: 3-term bf16 split of A and B (fp32-grade, argmax-safe). TERMS=1: plain bf16.
// AMODE: 0 = A row direct; 1 = compact (base+row); 2 = gather via flat[base+row].
// CMODE: 0 = C row direct; 1 = compact, masked row<cnt; 2 = scatter flat[base+row], masked.
template<int TERMS, int AMODE, int CMODE>
__global__ __launch_bounds__(256, 2)
void gemm_kernel(const float* __restrict__ A, const float* __restrict__ B,
                 float* __restrict__ C, int M, int N, int K,
                 const int* __restrict__ OFF, int eidx, const int* __restrict__ flat)
{
    int base = 0, cnt = M;
    if (AMODE != 0 || CMODE != 0) {
        base = OFF[eidx * 8];
        cnt  = OFF[eidx * 8 + 8] - base;
        if ((int)blockIdx.x * 128 >= cnt) return;
    }

    __shared__ unsigned short Ah[128 * 40];
    __shared__ unsigned short Bh[128 * 40];                      // transposed: Bh[n][k]
    __shared__ unsigned short Al [(TERMS == 6) ? 128 * 40 : 4];
    __shared__ unsigned short Al2[(TERMS == 6) ? 128 * 40 : 4];
    __shared__ unsigned short Bl [(TERMS == 6) ? 128 * 40 : 4];
    __shared__ unsigned short Bl2[(TERMS == 6) ? 128 * 40 : 4];

    const int tid   = threadIdx.x;
    const int lane  = tid & 63;
    const int wid   = tid >> 6;
    const int wm    = wid & 1, wn = wid >> 1;
    const int mlane = lane & 15, quad = lane >> 4;
    const int row0  = blockIdx.x * 128;
    const int col0  = blockIdx.y * 128;

    f32x4 acc[4][4];
#pragma unroll
    for (int i = 0; i < 4; ++i)
#pragma unroll
        for (int j = 0; j < 4; ++j)
#pragma unroll
            for (int r = 0; r < 4; ++r) acc[i][j][r] = 0.f;

    for (int k0 = 0; k0 < K; k0 += 32) {
        // ---- stage A ----
#pragma unroll
        for (int i = 0; i < 4; ++i) {
            int idx = tid + (i << 8);
            int r = idx >> 3;
            int c = (idx & 7) << 2;
            int lr = row0 + r;
            if (AMODE != 0) lr = min(lr, cnt - 1);
            size_t arow = (AMODE == 2) ? (size_t)flat[base + lr]
                        : (AMODE == 1) ? (size_t)(base + lr) : (size_t)lr;
            const float4 a = *(const float4*)(A + arow * K + k0 + c);
            float av[4] = {a.x, a.y, a.z, a.w};
            ushort4 hv, lv, l2v;
            unsigned short* hp  = (unsigned short*)&hv;
            unsigned short* lp  = (unsigned short*)&lv;
            unsigned short* l2p = (unsigned short*)&l2v;
#pragma unroll
            for (int j = 0; j < 4; ++j) {
                unsigned short h = f2bf(av[j]);
                hp[j] = h;
                if (TERMS == 6) {
                    float r1 = av[j] - bf2f(h);
                    unsigned short l = f2bf(r1);
                    lp[j]  = l;
                    l2p[j] = f2bf(r1 - bf2f(l));
                }
            }
            *(ushort4*)&Ah[r * 40 + c] = hv;
            if (TERMS == 6) {
                *(ushort4*)&Al [r * 40 + c] = lv;
                *(ushort4*)&Al2[r * 40 + c] = l2v;
            }
        }
        // ---- stage B (weights, full) ----
#pragma unroll
        for (int i = 0; i < 2; ++i) {
            int idx = tid + (i << 8);
            int kk = idx >> 4;
            int n8 = (idx & 15) << 3;
            const float* bp = B + (size_t)(k0 + kk) * N + col0 + n8;
            const float4 b0 = *(const float4*)bp;
            const float4 b1 = *(const float4*)(bp + 4);
            float bv[8] = {b0.x, b0.y, b0.z, b0.w, b1.x, b1.y, b1.z, b1.w};
#pragma unroll
            for (int j = 0; j < 8; ++j) {
                unsigned short h = f2bf(bv[j]);
                Bh[(n8 + j) * 40 + kk] = h;
                if (TERMS == 6) {
                    float r1 = bv[j] - bf2f(h);
                    unsigned short l = f2bf(r1);
                    Bl [(n8 + j) * 40 + kk] = l;
                    Bl2[(n8 + j) * 40 + kk] = f2bf(r1 - bf2f(l));
                }
            }
        }
        __syncthreads();

        bf16_8 fa[3][4], fb[3][4];
#pragma unroll
        for (int t = 0; t < 4; ++t) {
            int ar = (wm * 64 + t * 16 + mlane) * 40 + quad * 8;
            int br = (wn * 64 + t * 16 + mlane) * 40 + quad * 8;
            fa[0][t] = *(const bf16_8*)&Ah[ar];
            fb[0][t] = *(const bf16_8*)&Bh[br];
            if (TERMS == 6) {
                fa[1][t] = *(const bf16_8*)&Al[ar];
                fa[2][t] = *(const bf16_8*)&Al2[ar];
                fb[1][t] = *(const bf16_8*)&Bl[br];
                fb[2][t] = *(const bf16_8*)&Bl2[br];
            }
        }
        const int ta[6] = {0, 0, 1, 0, 1, 2};
        const int tb[6] = {0, 1, 0, 2, 1, 0};
#pragma unroll
        for (int s = 0; s < TERMS; ++s)
#pragma unroll
            for (int mt = 0; mt < 4; ++mt)
#pragma unroll
                for (int nt = 0; nt < 4; ++nt)
                    acc[mt][nt] = __builtin_amdgcn_mfma_f32_16x16x32_bf16(
                        fa[ta[s]][mt], fb[tb[s]][nt], acc[mt][nt], 0, 0, 0);
        __syncthreads();
    }

    // ---- epilogue: C/D layout col=lane&15, row=quad*4+reg ----
#pragma unroll
    for (int mt = 0; mt < 4; ++mt)
#pragma unroll
        for (int nt = 0; nt < 4; ++nt) {
            int c = col0 + wn * 64 + nt * 16 + mlane;
#pragma unroll
            for (int j = 0; j < 4; ++j) {
                int rel = wm * 64 + mt * 16 + quad * 4 + j;
                int lr  = row0 + rel;
                if (CMODE != 0 && lr >= cnt) continue;
                size_t crow = (CMODE == 2) ? (size_t)flat[base + lr]
                            : (CMODE == 1) ? (size_t)(base + lr) : (size_t)lr;
                C[crow * N + c] = acc[mt][nt][j];
            }
        }
}

// ---------- fp32 flash attention (shared block), d-sliced ----------
__global__ __launch_bounds__(256, 4)
void attn_kernel(const float* __restrict__ Q, const float* __restrict__ Km,
                 const float* __restrict__ V, float* __restrict__ O)
{
    __shared__ float ks[64][68];
    __shared__ float vs[64][68];

    const int tid = threadIdx.x;
    const int qt  = blockIdx.x & 15;
    const int h   = (blockIdx.x >> 4) & 7;
    const int b   = blockIdx.x >> 7;
    const size_t rowbase = (size_t)b * 1024;
    const int colbase = h * 64;
    const int q = tid >> 2, sub = tid & 3;
    const int ds = sub << 4;
    const size_t qrow = (rowbase + qt * 64 + q) * 512 + colbase;

    float4 qreg[4];
#pragma unroll
    for (int i = 0; i < 4; ++i) qreg[i] = *(const float4*)(Q + qrow + ds + i * 4);

    float4 oacc[4];
#pragma unroll
    for (int i = 0; i < 4; ++i) { oacc[i].x = oacc[i].y = oacc[i].z = oacc[i].w = 0.f; }
    float m = -1e30f, l = 0.f;

    for (int tt = 0; tt < 16; ++tt) {
        __syncthreads();
#pragma unroll
        for (int i = 0; i < 4; ++i) {
            int idx = tid + (i << 8);
            int r = idx >> 4, c = (idx & 15) << 2;
            const size_t g = (rowbase + tt * 64 + r) * 512 + colbase + c;
            *(float4*)&ks[r][c] = *(const float4*)(Km + g);
            *(float4*)&vs[r][c] = *(const float4*)(V + g);
        }
        __syncthreads();

#pragma unroll
        for (int c = 0; c < 4; ++c) {
            float s[16];
#pragma unroll
            for (int jj = 0; jj < 16; ++jj) {
                const int j = (c << 4) + jj;
                const float* kp = &ks[j][ds];
                float4 k0 = *(const float4*)kp;
                float4 k1 = *(const float4*)(kp + 4);
                float4 k2 = *(const float4*)(kp + 8);
                float4 k3 = *(const float4*)(kp + 12);
                float t = qreg[0].x * k0.x + qreg[0].y * k0.y + qreg[0].z * k0.z + qreg[0].w * k0.w
                        + qreg[1].x * k1.x + qreg[1].y * k1.y + qreg[1].z * k1.z + qreg[1].w * k1.w
                        + qreg[2].x * k2.x + qreg[2].y * k2.y + qreg[2].z * k2.z + qreg[2].w * k2.w
                        + qreg[3].x * k3.x + qreg[3].y * k3.y + qreg[3].z * k3.z + qreg[3].w * k3.w;
                t += __shfl_xor(t, 1);
                t += __shfl_xor(t, 2);
                s[jj] = t * 0.125f;
            }
            float mloc = s[0];
#pragma unroll
            for (int jj = 1; jj < 16; ++jj) mloc = fmaxf(mloc, s[jj]);
            float mnew = fmaxf(m, mloc);
            float alpha = __expf(m - mnew);
            float lt = 0.f;
#pragma unroll
            for (int jj = 0; jj < 16; ++jj) { s[jj] = __expf(s[jj] - mnew); lt += s[jj]; }
            l = l * alpha + lt;
#pragma unroll
            for (int i = 0; i < 4; ++i) {
                oacc[i].x *= alpha; oacc[i].y *= alpha;
                oacc[i].z *= alpha; oacc[i].w *= alpha;
            }
#pragma unroll
            for (int jj = 0; jj < 16; ++jj) {
                const float pj = s[jj];
                const float* vp = &vs[(c << 4) + jj][ds];
#pragma unroll
                for (int i = 0; i < 4; ++i) {
                    float4 v = *(const float4*)(vp + i * 4);
                    oacc[i].x += pj * v.x; oacc[i].y += pj * v.y;
                    oacc[i].z += pj * v.z; oacc[i].w += pj * v.w;
                }
            }
            m = mnew;
        }
    }

    const float inv = 1.f / l;
#pragma unroll
    for (int i = 0; i < 4; ++i) {
        float4 o;
        o.x = oacc[i].x * inv; o.y = oacc[i].y * inv;
        o.z = oacc[i].z * inv; o.w = oacc[i].w * inv;
        *(float4*)(O + qrow + ds + i * 4) = o;
    }
}

// ---------- compacted expert attention with zero-key correction ----------
// Compact rows per (e,b) bucket at OFF[e*8+b]. keys = c nonzero rows + (1024-c)
// zero keys (logit 0): m=max(m,0), l += (1024-c)*exp(-m). Writes AOc = attn - meanV.
__global__ __launch_bounds__(256, 4)
void attn_compact_kernel(const float* __restrict__ Qc, const float* __restrict__ Kc,
                         const float* __restrict__ Vc, const float* __restrict__ meanV,
                         float* __restrict__ AOc, const int* __restrict__ OFF)
{
    const int qt = blockIdx.x & 15;
    const int h  = (blockIdx.x >> 4) & 7;
    const int e  = (blockIdx.x >> 7) & 3;
    const int b  = blockIdx.x >> 9;
    const int base = OFF[e * 8 + b];
    const int c    = OFF[e * 8 + b + 1] - base;
    if (qt * 64 >= c) return;
    const int nq = min(64, c - qt * 64);

    __shared__ float ks[64][68];
    __shared__ float vs[64][68];

    const int tid = threadIdx.x;
    const int q = tid >> 2, sub = tid & 3;
    const int ds = sub << 4;
    const int colbase = h * 64;
    const size_t qrow = (size_t)(base + qt * 64 + min(q, nq - 1)) * 512 + colbase;

    float4 qreg[4];
#pragma unroll
    for (int i = 0; i < 4; ++i) qreg[i] = *(const float4*)(Qc + qrow + ds + i * 4);

    float4 oacc[4];
#pragma unroll
    for (int i = 0; i < 4; ++i) { oacc[i].x = oacc[i].y = oacc[i].z = oacc[i].w = 0.f; }
    float m = -1e30f, l = 0.f;

    for (int kt = 0; kt * 64 < c; ++kt) {
        const int cmax = c - kt * 64 - 1;
        __syncthreads();
#pragma unroll
        for (int i = 0; i < 4; ++i) {
            int idx = tid + (i << 8);
            int r = idx >> 4, cc = (idx & 15) << 2;
            const size_t g = (size_t)(base + kt * 64 + min(r, cmax)) * 512 + colbase + cc;
            *(float4*)&ks[r][cc] = *(const float4*)(Kc + g);
            *(float4*)&vs[r][cc] = *(const float4*)(Vc + g);
        }
        __syncthreads();

#pragma unroll
        for (int ch = 0; ch < 4; ++ch) {
            float s[16];
#pragma unroll
            for (int jj = 0; jj < 16; ++jj) {
                const int j = (ch << 4) + jj;
                const float* kp = &ks[j][ds];
                float4 k0 = *(const float4*)kp;
                float4 k1 = *(const float4*)(kp + 4);
                float4 k2 = *(const float4*)(kp + 8);
                float4 k3 = *(const float4*)(kp + 12);
                float t = qreg[0].x * k0.x + qreg[0].y * k0.y + qreg[0].z * k0.z + qreg[0].w * k0.w
                        + qreg[1].x * k1.x + qreg[1].y * k1.y + qreg[1].z * k1.z + qreg[1].w * k1.w
                        + qreg[2].x * k2.x + qreg[2].y * k2.y + qreg[2].z * k2.z + qreg[2].w * k2.w
                        + qreg[3].x * k3.x + qreg[3].y * k3.y + qreg[3].z * k3.z + qreg[3].w * k3.w;
                t += __shfl_xor(t, 1);
                t += __shfl_xor(t, 2);
                s[jj] = (kt * 64 + j < c) ? t * 0.125f : -1e30f;
            }
            float mloc = s[0];
#pragma unroll
            for (int jj = 1; jj < 16; ++jj) mloc = fmaxf(mloc, s[jj]);
            float mnew = fmaxf(m, mloc);
            float alpha = __expf(m - mnew);
            float lt = 0.f;
#pragma unroll
            for (int jj = 0; jj < 16; ++jj) { s[jj] = __expf(s[jj] - mnew); lt += s[jj]; }
            l = l * alpha + lt;
#pragma unroll
            for (int i = 0; i < 4; ++i) {
                oacc[i].x *= alpha; oacc[i].y *= alpha;
                oacc[i].z *= alpha; oacc[i].w *= alpha;
            }
#pragma unroll
            for (int jj = 0; jj < 16; ++jj) {
                const float pj = s[jj];
                const float* vp = &vs[(ch << 4) + jj][ds];
#pragma unroll
                for (int i = 0; i < 4; ++i) {
                    float4 v = *(const float4*)(vp + i * 4);
                    oacc[i].x += pj * v.x; oacc[i].y += pj * v.y;
                    oacc[i].z += pj * v.z; oacc[i].w += pj * v.w;
                }
            }
            m = mnew;
        }
    }

    // zero-key correction: (1024-c) keys with logit exactly 0
    float mfin = (c < 1024) ? fmaxf(m, 0.f) : m;
    float alphaf = __expf(m - mfin);
    l = l * alphaf + (float)(1024 - c) * __expf(-mfin);
#pragma unroll
    for (int i = 0; i < 4; ++i) {
        oacc[i].x *= alphaf; oacc[i].y *= alphaf;
        oacc[i].z *= alphaf; oacc[i].w *= alphaf;
    }

    if (q < nq) {
        const float inv = 1.f / l;
        const size_t orow = (size_t)(base + qt * 64 + q) * 512 + colbase;
        const float* mv = meanV + e * 65536 + b * 512 + colbase + ds;
#pragma unroll
        for (int i = 0; i < 4; ++i) {
            float4 mvv = *(const float4*)(mv + i * 4);
            float4 o;
            o.x = oacc[i].x * inv - mvv.x; o.y = oacc[i].y * inv - mvv.y;
            o.z = oacc[i].z * inv - mvv.z; o.w = oacc[i].w * inv - mvv.w;
            *(float4*)(AOc + orow + ds + i * 4) = o;
        }
    }
}

// ---------- meanV per (b,e,h): M32[e][b][h*64+d] = sum(Vc rows)/1024 ----------
__global__ void sumv_kernel(const float* __restrict__ Vc, const int* __restrict__ OFF,
                            float* __restrict__ M32)
{
    const int h = blockIdx.x & 7, e = (blockIdx.x >> 3) & 3, b = blockIdx.x >> 5;
    const int base = OFF[e * 8 + b], c = OFF[e * 8 + b + 1] - base;
    const int tid = threadIdx.x;
    const int d = tid & 63, g = tid >> 6;
    float s = 0.f;
    for (int r = g; r < c; r += 4) s += Vc[(size_t)(base + r) * 512 + h * 64 + d];
    __shared__ float red[256];
    red[tid] = s;
    __syncthreads();
    if (g == 0)
        M32[e * 65536 + b * 512 + h * 64 + d] =
            (red[d] + red[64 + d] + red[128 + d] + red[192 + d]) * (1.f / 1024.f);
}

// ---------- embedding gather ----------
__global__ void gather_kernel(const int* __restrict__ tokens,
                              const float* __restrict__ emb,
                              float* __restrict__ X)
{
    const int t = blockIdx.x;
    const int tok = tokens[t];
    const float4* src = (const float4*)(emb + (size_t)tok * 512);
    float4* dst = (float4*)(X + (size_t)t * 512);
    dst[threadIdx.x] = src[threadIdx.x];
}

// ---------- gate + argmax ----------
__global__ __launch_bounds__(256)
void gate_kernel(const float* __restrict__ H, const float* __restrict__ Wg,
                 int* __restrict__ idx)
{
    const int t = blockIdx.x * 4 + (threadIdx.x >> 6);
    const int lane = threadIdx.x & 63;
    float a0 = 0, a1 = 0, a2 = 0, a3 = 0;
#pragma unroll
    for (int i = 0; i < 8; ++i) {
        int d = i * 64 + lane;
        float hv = H[(size_t)t * 512 + d];
        a0 += hv * Wg[d * 4 + 0];
        a1 += hv * Wg[d * 4 + 1];
        a2 += hv * Wg[d * 4 + 2];
        a3 += hv * Wg[d * 4 + 3];
    }
#pragma unroll
    for (int off = 32; off > 0; off >>= 1) {
        a0 += __shfl_down(a0, off);
        a1 += __shfl_down(a1, off);
        a2 += __shfl_down(a2, off);
        a3 += __shfl_down(a3, off);
    }
    if (lane == 0) {
        int best = 0; float bv = a0;
        if (a1 > bv) { bv = a1; best = 1; }
        if (a2 > bv) { bv = a2; best = 2; }
        if (a3 > bv) { bv = a3; best = 3; }
        idx[t] = best;
    }
}

// ---------- compaction: count / offsets / fill ----------
__global__ void count_kernel(const int* __restrict__ idx, int* __restrict__ cnt)
{
    const int t = blockIdx.x * 256 + threadIdx.x;
    atomicAdd(&cnt[idx[t] * 8 + (t >> 10)], 1);
}
__global__ void offsets_kernel(const int* __restrict__ cnt, int* __restrict__ OFF,
                               int* __restrict__ cursor)
{
    if (threadIdx.x == 0) {
        int a = 0;
        for (int i = 0; i < 32; ++i) { OFF[i] = a; cursor[i] = a; a += cnt[i]; }
        OFF[32] = a;
    }
}
__global__ void fill_kernel(const int* __restrict__ idx, int* __restrict__ cursor,
                            int* __restrict__ flat)
{
    const int t = blockIdx.x * 256 + threadIdx.x;
    const int p = atomicAdd(&cursor[idx[t] * 8 + (t >> 10)], 1);
    flat[p] = t;
}

// ---------- SB[b] = sum_e G2[e][b][:] . Wout ----------
__global__ void sb_kernel(const float* __restrict__ G2, const float* __restrict__ Wout,
                          float* __restrict__ SB)
{
    const int tid = threadIdx.x;
    const int pair = tid >> 3, t8 = tid & 7;
    const int e = pair >> 3, b = pair & 7;
    float s = 0.f;
    for (int d = t8; d < 512; d += 8) s += G2[e * 65536 + b * 512 + d] * Wout[d];
    __shared__ float red[256];
    __shared__ float red2[32];
    red[tid] = s;
    __syncthreads();
    if (tid < 32) {
        float t = 0.f;
#pragma unroll
        for (int k = 0; k < 8; ++k) t += red[tid * 8 + k];
        red2[tid] = t;
    }
    __syncthreads();
    if (tid < 8)
        SB[tid] = red2[tid] + red2[8 + tid] + red2[16 + tid] + red2[24 + tid];
}

// ---------- head: out[t] = OA[t,:].Wout + SB[b(t)] ----------
__global__ __launch_bounds__(256)
void wout_kernel(const float* __restrict__ OUT, const float* __restrict__ Wout,
                 const float* __restrict__ SB, float* __restrict__ out)
{
    const int t = blockIdx.x * 4 + (threadIdx.x >> 6);
    const int lane = threadIdx.x & 63;
    float s = 0.f;
#pragma unroll
    for (int i = 0; i < 8; ++i) {
        int d = i * 64 + lane;
        s += OUT[(size_t)t * 512 + d] * Wout[d];
    }
#pragma unroll
    for (int off = 32; off > 0; off >>= 1) s += __shfl_down(s, off);
    if (lane == 0) out[t] = s + SB[t >> 10];
}

// ---------- launch ----------
extern "C" void kernel_launch(void* const* d_in, const int* in_sizes, int n_in,
                              void* d_out, int out_size, void* d_ws, size_t ws_size,
                              hipStream_t stream)
{
    const int*   tokens = (const int*)d_in[0];
    const float* emb  = (const float*)d_in[1];
    const float* Wq   = (const float*)d_in[2];
    const float* Wk   = (const float*)d_in[3];
    const float* Wv   = (const float*)d_in[4];
    const float* Wo   = (const float*)d_in[5];
    const float* W1   = (const float*)d_in[6];
    const float* W2   = (const float*)d_in[7];
    const float* Wg   = (const float*)d_in[8];
    const float* eWq  = (const float*)d_in[9];
    const float* eWk  = (const float*)d_in[10];
    const float* eWv  = (const float*)d_in[11];
    const float* eWo  = (const float*)d_in[12];
    const float* eW1  = (const float*)d_in[13];
    const float* eW2  = (const float*)d_in[14];
    const float* Wout = (const float*)d_in[15];
    float* outp = (float*)d_out;

    float* WS = (float*)d_ws;
    const size_t SZ = (size_t)8192 * 512;
    // planes: P0 X/T0c/G1, P1..P3 Qb,Kb,Vb / Qc,Kc,Vc (T1c spans P1..P4),
    //         P4 AO/AOc, P5 Hb, P6 OA, P7 misc
    float* X   = WS;
    float* Qb  = WS + SZ;
    float* Kb  = WS + 2 * SZ;
    float* Vb  = WS + 3 * SZ;
    float* AO  = WS + 4 * SZ;
    float* Hb  = WS + 5 * SZ;
    float* OA  = WS + 6 * SZ;
    float* Qc = Qb, *Kc = Kb, *Vc = Vb, *AOc = AO;
    float* T0c = X;
    float* T1c = Qb;            // [8192,2048] = P1..P4
    float* G1  = X;             // [4][128][2048] = 4 MB, after T0c dead

    int* ibase  = (int*)(WS + 7 * SZ);
    int* IDX    = ibase;
    int* cnt    = ibase + 8192;
    int* OFFp   = ibase + 8224;
    int* cursor = ibase + 8260;
    int* flat   = ibase + 8320;
    float* M32  = WS + 7 * SZ + 16640;      // [4][128][512]
    float* G0   = M32 + 262144;             // [4][128][512]
    float* G2   = G0 + 262144;              // [4][128][512]
    float* SB   = G2 + 262144;              // [8]

    const int M = 8192, D = 512, FF = 2048;
    dim3 gD(M / 128, D / 128), gF(M / 128, FF / 128);

    // ---- shared block: 6-term split GEMMs (argmax-safe) ----
    gather_kernel<<<8192, 128, 0, stream>>>(tokens, emb, X);
    gemm_kernel<6, 0, 0><<<gD, 256, 0, stream>>>(X,  Wq, Qb, M, D, D, nullptr, 0, nullptr);
    gemm_kernel<6, 0, 0><<<gD, 256, 0, stream>>>(X,  Wk, Kb, M, D, D, nullptr, 0, nullptr);
    gemm_kernel<6, 0, 0><<<gD, 256, 0, stream>>>(X,  Wv, Vb, M, D, D, nullptr, 0, nullptr);
    attn_kernel<<<1024, 256, 0, stream>>>(Qb, Kb, Vb, AO);
    gemm_kernel<6, 0, 0><<<gD, 256, 0, stream>>>(AO, Wo, X,  M, D, D, nullptr, 0, nullptr);
    gemm_kernel<6, 0, 0><<<gF, 256, 0, stream>>>(X,  W1, Qb, M, FF, D, nullptr, 0, nullptr);   // T1 in P1..P4
    gemm_kernel<6, 0, 0><<<gD, 256, 0, stream>>>(Qb, W2, Hb, M, D, FF, nullptr, 0, nullptr);
    gate_kernel<<<2048, 256, 0, stream>>>(Hb, Wg, IDX);

    // ---- compaction ----
    hipMemsetAsync(cnt, 0, 32 * sizeof(int), stream);
    hipMemsetAsync(M32, 0, 4 * 128 * 512 * sizeof(float), stream);
    count_kernel<<<32, 256, 0, stream>>>(IDX, cnt);
    offsets_kernel<<<1, 64, 0, stream>>>(cnt, OFFp, cursor);
    fill_kernel<<<32, 256, 0, stream>>>(IDX, cursor, flat);

    // ---- expert QKV on compacted rows (gather from Hb) ----
    for (int e = 0; e < 4; ++e) {
        gemm_kernel<1, 2, 1><<<gD, 256, 0, stream>>>(Hb, eWq + (size_t)e * D * D, Qc, M, D, D, OFFp, e, flat);
        gemm_kernel<1, 2, 1><<<gD, 256, 0, stream>>>(Hb, eWk + (size_t)e * D * D, Kc, M, D, D, OFFp, e, flat);
        gemm_kernel<1, 2, 1><<<gD, 256, 0, stream>>>(Hb, eWv + (size_t)e * D * D, Vc, M, D, D, OFFp, e, flat);
    }
    sumv_kernel<<<256, 256, 0, stream>>>(Vc, OFFp, M32);
    attn_compact_kernel<<<4096, 256, 0, stream>>>(Qc, Kc, Vc, M32, AOc, OFFp);

    // ---- expert FFN chain on compacted rows (R-path) ----
    for (int e = 0; e < 4; ++e)
        gemm_kernel<1, 1, 1><<<gD, 256, 0, stream>>>(AOc, eWo + (size_t)e * D * D, T0c, M, D, D, OFFp, e, flat);
    for (int e = 0; e < 4; ++e)
        gemm_kernel<1, 1, 1><<<gF, 256, 0, stream>>>(T0c, eW1 + (size_t)e * D * FF, T1c, M, FF, D, OFFp, e, flat);

    // ---- meanV path (M-path): tiny 128-row chains (rows 8..127 zero) ----
    for (int e = 0; e < 4; ++e) {
        gemm_kernel<1, 0, 0><<<dim3(1, 4),  256, 0, stream>>>(M32 + e * 65536, eWo + (size_t)e * D * D,  G0 + e * 65536, 128, D, D, nullptr, 0, nullptr);
        gemm_kernel<1, 0, 0><<<dim3(1, 16), 256, 0, stream>>>(G0 + e * 65536,  eW1 + (size_t)e * D * FF, G1 + e * 262144, 128, FF, D, nullptr, 0, nullptr);
        gemm_kernel<1, 0, 0><<<dim3(1, 4),  256, 0, stream>>>(G1 + e * 262144, eW2 + (size_t)e * FF * D, G2 + e * 65536, 128, D, FF, nullptr, 0, nullptr);
    }

    // ---- W2 on compacted rows, scatter into OA (each token written once) ----
    for (int e = 0; e < 4; ++e)
        gemm_kernel<1, 1, 2><<<gD, 256, 0, stream>>>(T1c, eW2 + (size_t)e * FF * D, OA, M, D, FF, OFFp, e, flat);

    sb_kernel<<<1, 256, 0, stream>>>(G2, Wout, SB);
    wout_kernel<<<2048, 256, 0, stream>>>(OA, Wout, SB, outp);
}

// Round 5
// 3131.571 us; speedup vs baseline: 1.8122x; 1.8122x over previous
//
#include <hip/hip_runtime.h>
#include <stdint.h>
#include <stddef.h>

// ---------- types ----------
typedef __bf16 bf16_8 __attribute__((ext_vector_type(8)));
typedef float  f32x4  __attribute__((ext_vector_type(4)));

__device__ __forceinline__ unsigned short f2bf(float f) {
    unsigned u = __float_as_uint(f);
    unsigned r = (u + 0x7fffu + ((u >> 16) & 1u)) >> 16;   // RTN-even
    return (unsigned short)r;
}
__device__ __forceinline__ float bf2f(unsigned short s) {
    return __uint_as_float(((unsigned)s) << 16);
}

// ---------- GEMM: C = A[M,K](f32) * B[K,N](f32) via bf16 MFMA, expert-batched in z ----------
// 128x128 tile, BK=32, 256 threads (2x2 waves x 4x4 MFMA 16x16x32).
// TERMS=6: 3-term bf16 split of A and B (fp32-grade, argmax-safe). TERMS=1: plain bf16.
// AMODE: 0 direct (+e*astride); 1 compact base+row; 2 gather flat[base+row].
// CMODE: 0 direct (+e*cstride); 1 compact masked; 2 scatter flat[base+row] masked.
// NW weights per expert in z: z = e*NW + w. B = Bw + e*bstride, C = Cw (+e*cstride).
template<int TERMS, int AMODE, int CMODE, int NW>
__global__ __launch_bounds__(256, 2)
void gemm_kernel(const float* __restrict__ A,
                 const float* __restrict__ B0, const float* __restrict__ B1, const float* __restrict__ B2,
                 float* __restrict__ C0, float* __restrict__ C1, float* __restrict__ C2,
                 int M, int N, int K,
                 size_t astride, size_t bstride, size_t cstride,
                 const int* __restrict__ OFF, const int* __restrict__ flat)
{
    const int z = blockIdx.z;
    const int e = z / NW, w = z % NW;

    int base = 0, cnt = M;
    if (AMODE == 1 || AMODE == 2 || CMODE == 1 || CMODE == 2) {
        base = OFF[e * 8];
        cnt  = OFF[e * 8 + 8] - base;
        if ((int)blockIdx.x * 128 >= cnt) return;
    }
    const float* Ae = A + (size_t)e * astride;
    const float* B  = (NW == 3 ? (w == 0 ? B0 : (w == 1 ? B1 : B2)) : B0) + (size_t)e * bstride;
    float*       C  = (NW == 3 ? (w == 0 ? C0 : (w == 1 ? C1 : C2)) : C0) + (size_t)e * cstride;

    __shared__ unsigned short Ah[128 * 40];
    __shared__ unsigned short Bh[128 * 40];                      // transposed: Bh[n][k]
    __shared__ unsigned short Al [(TERMS == 6) ? 128 * 40 : 4];
    __shared__ unsigned short Al2[(TERMS == 6) ? 128 * 40 : 4];
    __shared__ unsigned short Bl [(TERMS == 6) ? 128 * 40 : 4];
    __shared__ unsigned short Bl2[(TERMS == 6) ? 128 * 40 : 4];

    const int tid   = threadIdx.x;
    const int lane  = tid & 63;
    const int wid   = tid >> 6;
    const int wm    = wid & 1, wn = wid >> 1;
    const int mlane = lane & 15, quad = lane >> 4;
    const int row0  = blockIdx.x * 128;
    const int col0  = blockIdx.y * 128;

    f32x4 acc[4][4];
#pragma unroll
    for (int i = 0; i < 4; ++i)
#pragma unroll
        for (int j = 0; j < 4; ++j)
#pragma unroll
            for (int r = 0; r < 4; ++r) acc[i][j][r] = 0.f;

    for (int k0 = 0; k0 < K; k0 += 32) {
        // ---- stage A ----
#pragma unroll
        for (int i = 0; i < 4; ++i) {
            int idx = tid + (i << 8);
            int r = idx >> 3;
            int c = (idx & 7) << 2;
            int lr = row0 + r;
            if (AMODE != 0) lr = min(lr, cnt - 1);
            size_t arow = (AMODE == 2) ? (size_t)flat[base + lr]
                        : (AMODE == 1) ? (size_t)(base + lr) : (size_t)lr;
            const float4 a = *(const float4*)(Ae + arow * K + k0 + c);
            float av[4] = {a.x, a.y, a.z, a.w};
            ushort4 hv, lv, l2v;
            unsigned short* hp  = (unsigned short*)&hv;
            unsigned short* lp  = (unsigned short*)&lv;
            unsigned short* l2p = (unsigned short*)&l2v;
#pragma unroll
            for (int j = 0; j < 4; ++j) {
                unsigned short h = f2bf(av[j]);
                hp[j] = h;
                if (TERMS == 6) {
                    float r1 = av[j] - bf2f(h);
                    unsigned short l = f2bf(r1);
                    lp[j]  = l;
                    l2p[j] = f2bf(r1 - bf2f(l));
                }
            }
            *(ushort4*)&Ah[r * 40 + c] = hv;
            if (TERMS == 6) {
                *(ushort4*)&Al [r * 40 + c] = lv;
                *(ushort4*)&Al2[r * 40 + c] = l2v;
            }
        }
        // ---- stage B (weights, full) ----
#pragma unroll
        for (int i = 0; i < 2; ++i) {
            int idx = tid + (i << 8);
            int kk = idx >> 4;
            int n8 = (idx & 15) << 3;
            const float* bp = B + (size_t)(k0 + kk) * N + col0 + n8;
            const float4 b0 = *(const float4*)bp;
            const float4 b1 = *(const float4*)(bp + 4);
            float bv[8] = {b0.x, b0.y, b0.z, b0.w, b1.x, b1.y, b1.z, b1.w};
#pragma unroll
            for (int j = 0; j < 8; ++j) {
                unsigned short h = f2bf(bv[j]);
                Bh[(n8 + j) * 40 + kk] = h;
                if (TERMS == 6) {
                    float r1 = bv[j] - bf2f(h);
                    unsigned short l = f2bf(r1);
                    Bl [(n8 + j) * 40 + kk] = l;
                    Bl2[(n8 + j) * 40 + kk] = f2bf(r1 - bf2f(l));
                }
            }
        }
        __syncthreads();

        bf16_8 fa[3][4], fb[3][4];
#pragma unroll
        for (int t = 0; t < 4; ++t) {
            int ar = (wm * 64 + t * 16 + mlane) * 40 + quad * 8;
            int br = (wn * 64 + t * 16 + mlane) * 40 + quad * 8;
            fa[0][t] = *(const bf16_8*)&Ah[ar];
            fb[0][t] = *(const bf16_8*)&Bh[br];
            if (TERMS == 6) {
                fa[1][t] = *(const bf16_8*)&Al[ar];
                fa[2][t] = *(const bf16_8*)&Al2[ar];
                fb[1][t] = *(const bf16_8*)&Bl[br];
                fb[2][t] = *(const bf16_8*)&Bl2[br];
            }
        }
        const int ta[6] = {0, 0, 1, 0, 1, 2};
        const int tb[6] = {0, 1, 0, 2, 1, 0};
#pragma unroll
        for (int s = 0; s < TERMS; ++s)
#pragma unroll
            for (int mt = 0; mt < 4; ++mt)
#pragma unroll
                for (int nt = 0; nt < 4; ++nt)
                    acc[mt][nt] = __builtin_amdgcn_mfma_f32_16x16x32_bf16(
                        fa[ta[s]][mt], fb[tb[s]][nt], acc[mt][nt], 0, 0, 0);
        __syncthreads();
    }

    // ---- epilogue: C/D layout col=lane&15, row=quad*4+reg ----
#pragma unroll
    for (int mt = 0; mt < 4; ++mt)
#pragma unroll
        for (int nt = 0; nt < 4; ++nt) {
            int c = col0 + wn * 64 + nt * 16 + mlane;
#pragma unroll
            for (int j = 0; j < 4; ++j) {
                int lr = row0 + wm * 64 + mt * 16 + quad * 4 + j;
                if ((CMODE == 1 || CMODE == 2) && lr >= cnt) continue;
                size_t crow = (CMODE == 2) ? (size_t)flat[base + lr]
                            : (CMODE == 1) ? (size_t)(base + lr) : (size_t)lr;
                C[crow * N + c] = acc[mt][nt][j];
            }
        }
}

// ---------- fp32 flash attention (shared block), d-sliced ----------
__global__ __launch_bounds__(256, 4)
void attn_kernel(const float* __restrict__ Q, const float* __restrict__ Km,
                 const float* __restrict__ V, float* __restrict__ O)
{
    __shared__ float ks[64][68];
    __shared__ float vs[64][68];

    const int tid = threadIdx.x;
    const int qt  = blockIdx.x & 15;
    const int h   = (blockIdx.x >> 4) & 7;
    const int b   = blockIdx.x >> 7;
    const size_t rowbase = (size_t)b * 1024;
    const int colbase = h * 64;
    const int q = tid >> 2, sub = tid & 3;
    const int ds = sub << 4;
    const size_t qrow = (rowbase + qt * 64 + q) * 512 + colbase;

    float4 qreg[4];
#pragma unroll
    for (int i = 0; i < 4; ++i) qreg[i] = *(const float4*)(Q + qrow + ds + i * 4);

    float4 oacc[4];
#pragma unroll
    for (int i = 0; i < 4; ++i) { oacc[i].x = oacc[i].y = oacc[i].z = oacc[i].w = 0.f; }
    float m = -1e30f, l = 0.f;

    for (int tt = 0; tt < 16; ++tt) {
        __syncthreads();
#pragma unroll
        for (int i = 0; i < 4; ++i) {
            int idx = tid + (i << 8);
            int r = idx >> 4, c = (idx & 15) << 2;
            const size_t g = (rowbase + tt * 64 + r) * 512 + colbase + c;
            *(float4*)&ks[r][c] = *(const float4*)(Km + g);
            *(float4*)&vs[r][c] = *(const float4*)(V + g);
        }
        __syncthreads();

#pragma unroll
        for (int c = 0; c < 4; ++c) {
            float s[16];
#pragma unroll
            for (int jj = 0; jj < 16; ++jj) {
                const int j = (c << 4) + jj;
                const float* kp = &ks[j][ds];
                float4 k0 = *(const float4*)kp;
                float4 k1 = *(const float4*)(kp + 4);
                float4 k2 = *(const float4*)(kp + 8);
                float4 k3 = *(const float4*)(kp + 12);
                float t = qreg[0].x * k0.x + qreg[0].y * k0.y + qreg[0].z * k0.z + qreg[0].w * k0.w
                        + qreg[1].x * k1.x + qreg[1].y * k1.y + qreg[1].z * k1.z + qreg[1].w * k1.w
                        + qreg[2].x * k2.x + qreg[2].y * k2.y + qreg[2].z * k2.z + qreg[2].w * k2.w
                        + qreg[3].x * k3.x + qreg[3].y * k3.y + qreg[3].z * k3.z + qreg[3].w * k3.w;
                t += __shfl_xor(t, 1);
                t += __shfl_xor(t, 2);
                s[jj] = t * 0.125f;
            }
            float mloc = s[0];
#pragma unroll
            for (int jj = 1; jj < 16; ++jj) mloc = fmaxf(mloc, s[jj]);
            float mnew = fmaxf(m, mloc);
            float alpha = __expf(m - mnew);
            float lt = 0.f;
#pragma unroll
            for (int jj = 0; jj < 16; ++jj) { s[jj] = __expf(s[jj] - mnew); lt += s[jj]; }
            l = l * alpha + lt;
#pragma unroll
            for (int i = 0; i < 4; ++i) {
                oacc[i].x *= alpha; oacc[i].y *= alpha;
                oacc[i].z *= alpha; oacc[i].w *= alpha;
            }
#pragma unroll
            for (int jj = 0; jj < 16; ++jj) {
                const float pj = s[jj];
                const float* vp = &vs[(c << 4) + jj][ds];
#pragma unroll
                for (int i = 0; i < 4; ++i) {
                    float4 v = *(const float4*)(vp + i * 4);
                    oacc[i].x += pj * v.x; oacc[i].y += pj * v.y;
                    oacc[i].z += pj * v.z; oacc[i].w += pj * v.w;
                }
            }
            m = mnew;
        }
    }

    const float inv = 1.f / l;
#pragma unroll
    for (int i = 0; i < 4; ++i) {
        float4 o;
        o.x = oacc[i].x * inv; o.y = oacc[i].y * inv;
        o.z = oacc[i].z * inv; o.w = oacc[i].w * inv;
        *(float4*)(O + qrow + ds + i * 4) = o;
    }
}

// ---------- compacted expert attention with zero-key correction ----------
__global__ __launch_bounds__(256, 4)
void attn_compact_kernel(const float* __restrict__ Qc, const float* __restrict__ Kc,
                         const float* __restrict__ Vc, const float* __restrict__ meanV,
                         float* __restrict__ AOc, const int* __restrict__ OFF)
{
    const int qt = blockIdx.x & 15;
    const int h  = (blockIdx.x >> 4) & 7;
    const int e  = (blockIdx.x >> 7) & 3;
    const int b  = blockIdx.x >> 9;
    const int base = OFF[e * 8 + b];
    const int c    = OFF[e * 8 + b + 1] - base;
    if (qt * 64 >= c) return;
    const int nq = min(64, c - qt * 64);

    __shared__ float ks[64][68];
    __shared__ float vs[64][68];

    const int tid = threadIdx.x;
    const int q = tid >> 2, sub = tid & 3;
    const int ds = sub << 4;
    const int colbase = h * 64;
    const size_t qrow = (size_t)(base + qt * 64 + min(q, nq - 1)) * 512 + colbase;

    float4 qreg[4];
#pragma unroll
    for (int i = 0; i < 4; ++i) qreg[i] = *(const float4*)(Qc + qrow + ds + i * 4);

    float4 oacc[4];
#pragma unroll
    for (int i = 0; i < 4; ++i) { oacc[i].x = oacc[i].y = oacc[i].z = oacc[i].w = 0.f; }
    float m = -1e30f, l = 0.f;

    for (int kt = 0; kt * 64 < c; ++kt) {
        const int cmax = c - kt * 64 - 1;
        __syncthreads();
#pragma unroll
        for (int i = 0; i < 4; ++i) {
            int idx = tid + (i << 8);
            int r = idx >> 4, cc = (idx & 15) << 2;
            const size_t g = (size_t)(base + kt * 64 + min(r, cmax)) * 512 + colbase + cc;
            *(float4*)&ks[r][cc] = *(const float4*)(Kc + g);
            *(float4*)&vs[r][cc] = *(const float4*)(Vc + g);
        }
        __syncthreads();

#pragma unroll
        for (int ch = 0; ch < 4; ++ch) {
            float s[16];
#pragma unroll
            for (int jj = 0; jj < 16; ++jj) {
                const int j = (ch << 4) + jj;
                const float* kp = &ks[j][ds];
                float4 k0 = *(const float4*)kp;
                float4 k1 = *(const float4*)(kp + 4);
                float4 k2 = *(const float4*)(kp + 8);
                float4 k3 = *(const float4*)(kp + 12);
                float t = qreg[0].x * k0.x + qreg[0].y * k0.y + qreg[0].z * k0.z + qreg[0].w * k0.w
                        + qreg[1].x * k1.x + qreg[1].y * k1.y + qreg[1].z * k1.z + qreg[1].w * k1.w
                        + qreg[2].x * k2.x + qreg[2].y * k2.y + qreg[2].z * k2.z + qreg[2].w * k2.w
                        + qreg[3].x * k3.x + qreg[3].y * k3.y + qreg[3].z * k3.z + qreg[3].w * k3.w;
                t += __shfl_xor(t, 1);
                t += __shfl_xor(t, 2);
                s[jj] = (kt * 64 + j < c) ? t * 0.125f : -1e30f;
            }
            float mloc = s[0];
#pragma unroll
            for (int jj = 1; jj < 16; ++jj) mloc = fmaxf(mloc, s[jj]);
            float mnew = fmaxf(m, mloc);
            float alpha = __expf(m - mnew);
            float lt = 0.f;
#pragma unroll
            for (int jj = 0; jj < 16; ++jj) { s[jj] = __expf(s[jj] - mnew); lt += s[jj]; }
            l = l * alpha + lt;
#pragma unroll
            for (int i = 0; i < 4; ++i) {
                oacc[i].x *= alpha; oacc[i].y *= alpha;
                oacc[i].z *= alpha; oacc[i].w *= alpha;
            }
#pragma unroll
            for (int jj = 0; jj < 16; ++jj) {
                const float pj = s[jj];
                const float* vp = &vs[(ch << 4) + jj][ds];
#pragma unroll
                for (int i = 0; i < 4; ++i) {
                    float4 v = *(const float4*)(vp + i * 4);
                    oacc[i].x += pj * v.x; oacc[i].y += pj * v.y;
                    oacc[i].z += pj * v.z; oacc[i].w += pj * v.w;
                }
            }
            m = mnew;
        }
    }

    // zero-key correction: (1024-c) keys with logit exactly 0
    float mfin = (c < 1024) ? fmaxf(m, 0.f) : m;
    float alphaf = __expf(m - mfin);
    l = l * alphaf + (float)(1024 - c) * __expf(-mfin);
#pragma unroll
    for (int i = 0; i < 4; ++i) {
        oacc[i].x *= alphaf; oacc[i].y *= alphaf;
        oacc[i].z *= alphaf; oacc[i].w *= alphaf;
    }

    if (q < nq) {
        const float inv = 1.f / l;
        const size_t orow = (size_t)(base + qt * 64 + q) * 512 + colbase;
        const float* mv = meanV + e * 65536 + b * 512 + colbase + ds;
#pragma unroll
        for (int i = 0; i < 4; ++i) {
            float4 mvv = *(const float4*)(mv + i * 4);
            float4 o;
            o.x = oacc[i].x * inv - mvv.x; o.y = oacc[i].y * inv - mvv.y;
            o.z = oacc[i].z * inv - mvv.z; o.w = oacc[i].w * inv - mvv.w;
            *(float4*)(AOc + orow + ds + i * 4) = o;
        }
    }
}

// ---------- meanV per (b,e,h): M32[e][b][h*64+d] = sum(Vc rows)/1024 ----------
__global__ void sumv_kernel(const float* __restrict__ Vc, const int* __restrict__ OFF,
                            float* __restrict__ M32)
{
    const int h = blockIdx.x & 7, e = (blockIdx.x >> 3) & 3, b = blockIdx.x >> 5;
    const int base = OFF[e * 8 + b], c = OFF[e * 8 + b + 1] - base;
    const int tid = threadIdx.x;
    const int d = tid & 63, g = tid >> 6;
    float s = 0.f;
    for (int r = g; r < c; r += 4) s += Vc[(size_t)(base + r) * 512 + h * 64 + d];
    __shared__ float red[256];
    red[tid] = s;
    __syncthreads();
    if (g == 0)
        M32[e * 65536 + b * 512 + h * 64 + d] =
            (red[d] + red[64 + d] + red[128 + d] + red[192 + d]) * (1.f / 1024.f);
}

// ---------- embedding gather ----------
__global__ void gather_kernel(const int* __restrict__ tokens,
                              const float* __restrict__ emb,
                              float* __restrict__ X)
{
    const int t = blockIdx.x;
    const int tok = tokens[t];
    const float4* src = (const float4*)(emb + (size_t)tok * 512);
    float4* dst = (float4*)(X + (size_t)t * 512);
    dst[threadIdx.x] = src[threadIdx.x];
}

// ---------- gate + argmax ----------
__global__ __launch_bounds__(256)
void gate_kernel(const float* __restrict__ H, const float* __restrict__ Wg,
                 int* __restrict__ idx)
{
    const int t = blockIdx.x * 4 + (threadIdx.x >> 6);
    const int lane = threadIdx.x & 63;
    float a0 = 0, a1 = 0, a2 = 0, a3 = 0;
#pragma unroll
    for (int i = 0; i < 8; ++i) {
        int d = i * 64 + lane;
        float hv = H[(size_t)t * 512 + d];
        a0 += hv * Wg[d * 4 + 0];
        a1 += hv * Wg[d * 4 + 1];
        a2 += hv * Wg[d * 4 + 2];
        a3 += hv * Wg[d * 4 + 3];
    }
#pragma unroll
    for (int off = 32; off > 0; off >>= 1) {
        a0 += __shfl_down(a0, off);
        a1 += __shfl_down(a1, off);
        a2 += __shfl_down(a2, off);
        a3 += __shfl_down(a3, off);
    }
    if (lane == 0) {
        int best = 0; float bv = a0;
        if (a1 > bv) { bv = a1; best = 1; }
        if (a2 > bv) { bv = a2; best = 2; }
        if (a3 > bv) { bv = a3; best = 3; }
        idx[t] = best;
    }
}

// ---------- compaction: count / offsets / fill ----------
__global__ void count_kernel(const int* __restrict__ idx, int* __restrict__ cnt)
{
    const int t = blockIdx.x * 256 + threadIdx.x;
    atomicAdd(&cnt[idx[t] * 8 + (t >> 10)], 1);
}
__global__ void offsets_kernel(const int* __restrict__ cnt, int* __restrict__ OFF,
                               int* __restrict__ cursor)
{
    if (threadIdx.x == 0) {
        int a = 0;
        for (int i = 0; i < 32; ++i) { OFF[i] = a; cursor[i] = a; a += cnt[i]; }
        OFF[32] = a;
    }
}
__global__ void fill_kernel(const int* __restrict__ idx, int* __restrict__ cursor,
                            int* __restrict__ flat)
{
    const int t = blockIdx.x * 256 + threadIdx.x;
    const int p = atomicAdd(&cursor[idx[t] * 8 + (t >> 10)], 1);
    flat[p] = t;
}

// ---------- SB[b] = sum_e G2[e][b][:] . Wout ----------
__global__ void sb_kernel(const float* __restrict__ G2, const float* __restrict__ Wout,
                          float* __restrict__ SB)
{
    const int tid = threadIdx.x;
    const int pair = tid >> 3, t8 = tid & 7;
    const int e = pair >> 3, b = pair & 7;
    float s = 0.f;
    for (int d = t8; d < 512; d += 8) s += G2[e * 65536 + b * 512 + d] * Wout[d];
    __shared__ float red[256];
    __shared__ float red2[32];
    red[tid] = s;
    __syncthreads();
    if (tid < 32) {
        float t = 0.f;
#pragma unroll
        for (int k = 0; k < 8; ++k) t += red[tid * 8 + k];
        red2[tid] = t;
    }
    __syncthreads();
    if (tid < 8)
        SB[tid] = red2[tid] + red2[8 + tid] + red2[16 + tid] + red2[24 + tid];
}

// ---------- head: out[t] = OA[t,:].Wout + SB[b(t)] ----------
__global__ __launch_bounds__(256)
void wout_kernel(const float* __restrict__ OUT, const float* __restrict__ Wout,
                 const float* __restrict__ SB, float* __restrict__ out)
{
    const int t = blockIdx.x * 4 + (threadIdx.x >> 6);
    const int lane = threadIdx.x & 63;
    float s = 0.f;
#pragma unroll
    for (int i = 0; i < 8; ++i) {
        int d = i * 64 + lane;
        s += OUT[(size_t)t * 512 + d] * Wout[d];
    }
#pragma unroll
    for (int off = 32; off > 0; off >>= 1) s += __shfl_down(s, off);
    if (lane == 0) out[t] = s + SB[t >> 10];
}

// ---------- launch ----------
extern "C" void kernel_launch(void* const* d_in, const int* in_sizes, int n_in,
                              void* d_out, int out_size, void* d_ws, size_t ws_size,
                              hipStream_t stream)
{
    const int*   tokens = (const int*)d_in[0];
    const float* emb  = (const float*)d_in[1];
    const float* Wq   = (const float*)d_in[2];
    const float* Wk   = (const float*)d_in[3];
    const float* Wv   = (const float*)d_in[4];
    const float* Wo   = (const float*)d_in[5];
    const float* W1   = (const float*)d_in[6];
    const float* W2   = (const float*)d_in[7];
    const float* Wg   = (const float*)d_in[8];
    const float* eWq  = (const float*)d_in[9];
    const float* eWk  = (const float*)d_in[10];
    const float* eWv  = (const float*)d_in[11];
    const float* eWo  = (const float*)d_in[12];
    const float* eW1  = (const float*)d_in[13];
    const float* eW2  = (const float*)d_in[14];
    const float* Wout = (const float*)d_in[15];
    float* outp = (float*)d_out;

    float* WS = (float*)d_ws;
    const size_t SZ = (size_t)8192 * 512;
    float* X   = WS;
    float* Qb  = WS + SZ;
    float* Kb  = WS + 2 * SZ;
    float* Vb  = WS + 3 * SZ;
    float* AO  = WS + 4 * SZ;
    float* Hb  = WS + 5 * SZ;
    float* OA  = WS + 6 * SZ;
    float* Qc = Qb, *Kc = Kb, *Vc = Vb, *AOc = AO;
    float* T0c = X;
    float* T1c = Qb;            // [8192,2048] = P1..P4
    float* G1  = X;             // [4][128][2048] = 4 MB, after T0c dead

    int* ibase  = (int*)(WS + 7 * SZ);
    int* IDX    = ibase;
    int* cnt    = ibase + 8192;
    int* OFFp   = ibase + 8224;
    int* cursor = ibase + 8260;
    int* flat   = ibase + 8320;
    float* M32  = WS + 7 * SZ + 16640;      // [4][128][512]
    float* G0   = M32 + 262144;             // [4][128][512]
    float* G2   = G0 + 262144;              // [4][128][512]
    float* SB   = G2 + 262144;              // [8]

    const int M = 8192, D = 512, FF = 2048;
    const size_t sDD = (size_t)D * D, sDF = (size_t)D * FF;
    const float* NUL = nullptr;
    float* NULm = nullptr;

    // ---- shared block: 6-term split GEMMs (argmax-safe), QKV batched in z ----
    gather_kernel<<<8192, 128, 0, stream>>>(tokens, emb, X);
    gemm_kernel<6, 0, 0, 3><<<dim3(64, 4, 3), 256, 0, stream>>>(
        X, Wq, Wk, Wv, Qb, Kb, Vb, M, D, D, 0, 0, 0, nullptr, nullptr);
    attn_kernel<<<1024, 256, 0, stream>>>(Qb, Kb, Vb, AO);
    gemm_kernel<6, 0, 0, 1><<<dim3(64, 4, 1), 256, 0, stream>>>(
        AO, Wo, NUL, NUL, X, NULm, NULm, M, D, D, 0, 0, 0, nullptr, nullptr);
    gemm_kernel<6, 0, 0, 1><<<dim3(64, 16, 1), 256, 0, stream>>>(
        X, W1, NUL, NUL, Qb, NULm, NULm, M, FF, D, 0, 0, 0, nullptr, nullptr);   // T1 in P1..P4
    gemm_kernel<6, 0, 0, 1><<<dim3(64, 4, 1), 256, 0, stream>>>(
        Qb, W2, NUL, NUL, Hb, NULm, NULm, M, D, FF, 0, 0, 0, nullptr, nullptr);
    gate_kernel<<<2048, 256, 0, stream>>>(Hb, Wg, IDX);

    // ---- compaction ----
    hipMemsetAsync(cnt, 0, 32 * sizeof(int), stream);
    hipMemsetAsync(M32, 0, 4 * 128 * 512 * sizeof(float), stream);
    count_kernel<<<32, 256, 0, stream>>>(IDX, cnt);
    offsets_kernel<<<1, 64, 0, stream>>>(cnt, OFFp, cursor);
    fill_kernel<<<32, 256, 0, stream>>>(IDX, cursor, flat);

    // ---- expert QKV: one launch, z = e*3 + {q,k,v} (gather rows from Hb) ----
    gemm_kernel<1, 2, 1, 3><<<dim3(64, 4, 12), 256, 0, stream>>>(
        Hb, eWq, eWk, eWv, Qc, Kc, Vc, M, D, D, 0, sDD, 0, OFFp, flat);
    sumv_kernel<<<256, 256, 0, stream>>>(Vc, OFFp, M32);
    attn_compact_kernel<<<4096, 256, 0, stream>>>(Qc, Kc, Vc, M32, AOc, OFFp);

    // ---- expert FFN chain on compacted rows (R-path), batched z=4 ----
    gemm_kernel<1, 1, 1, 1><<<dim3(64, 4, 4), 256, 0, stream>>>(
        AOc, eWo, NUL, NUL, T0c, NULm, NULm, M, D, D, 0, sDD, 0, OFFp, flat);
    gemm_kernel<1, 1, 1, 1><<<dim3(64, 16, 4), 256, 0, stream>>>(
        T0c, eW1, NUL, NUL, T1c, NULm, NULm, M, FF, D, 0, sDF, 0, OFFp, flat);

    // ---- meanV path (M-path): 3 batched launches, 128-row tiles (rows 8+ zero) ----
    gemm_kernel<1, 0, 0, 1><<<dim3(1, 4, 4), 256, 0, stream>>>(
        M32, eWo, NUL, NUL, G0, NULm, NULm, 128, D, D, 65536, sDD, 65536, nullptr, nullptr);
    gemm_kernel<1, 0, 0, 1><<<dim3(1, 16, 4), 256, 0, stream>>>(
        G0, eW1, NUL, NUL, G1, NULm, NULm, 128, FF, D, 65536, sDF, 262144, nullptr, nullptr);
    gemm_kernel<1, 0, 0, 1><<<dim3(1, 4, 4), 256, 0, stream>>>(
        G1, eW2, NUL, NUL, G2, NULm, NULm, 128, D, FF, 262144, sDF, 65536, nullptr, nullptr);

    // ---- W2 on compacted rows, scatter into OA (each token written once) ----
    gemm_kernel<1, 1, 2, 1><<<dim3(64, 4, 4), 256, 0, stream>>>(
        T1c, eW2, NUL, NUL, OA, NULm, NULm, M, D, FF, 0, sDF, 0, OFFp, flat);

    sb_kernel<<<1, 256, 0, stream>>>(G2, Wout, SB);
    wout_kernel<<<2048, 256, 0, stream>>>(OA, Wout, SB, outp);
}

// Round 6
// 2284.796 us; speedup vs baseline: 2.4839x; 1.3706x over previous
//
#include <hip/hip_runtime.h>
#include <stdint.h>
#include <stddef.h>

// ---------- types ----------
typedef __bf16 bf16_8 __attribute__((ext_vector_type(8)));
typedef float  f32x4  __attribute__((ext_vector_type(4)));

__device__ __forceinline__ unsigned short f2bf(float f) {
    unsigned u = __float_as_uint(f);
    unsigned r = (u + 0x7fffu + ((u >> 16) & 1u)) >> 16;   // RTN-even
    return (unsigned short)r;
}
__device__ __forceinline__ float bf2f(unsigned short s) {
    return __uint_as_float(((unsigned)s) << 16);
}

// ---------- weight transpose+split: src [K][N] f32 -> dst planes [P][N][K] bf16 ----------
template<int P>
__global__ __launch_bounds__(256)
void wsplit_kernel(const float* __restrict__ s0, const float* __restrict__ s1,
                   const float* __restrict__ s2, const float* __restrict__ s3,
                   unsigned short* __restrict__ d0, unsigned short* __restrict__ d1,
                   unsigned short* __restrict__ d2, unsigned short* __restrict__ d3,
                   int K, int N, int nper, size_t sstride, size_t dstride)
{
    const int z = blockIdx.z;
    const int arr = z / nper, e = z - arr * nper;
    const float* src = (arr == 0 ? s0 : arr == 1 ? s1 : arr == 2 ? s2 : s3) + (size_t)e * sstride;
    unsigned short* dst = (arr == 0 ? d0 : arr == 1 ? d1 : arr == 2 ? d2 : d3) + (size_t)e * dstride;
    const size_t NK = (size_t)N * K;
    __shared__ float T[64][65];
    const int n0 = blockIdx.x * 64, k0 = blockIdx.y * 64;
    const int tid = threadIdx.x;
#pragma unroll
    for (int i = 0; i < 16; ++i) {
        int idx = tid + (i << 8);
        int kk = idx >> 6, nn = idx & 63;
        T[kk][nn] = src[(size_t)(k0 + kk) * N + n0 + nn];
    }
    __syncthreads();
#pragma unroll
    for (int i = 0; i < 4; ++i) {
        int idx = (tid + (i << 8)) << 2;
        int nn = idx >> 6, kk = idx & 63;
        ushort4 hv, lv, l2v;
        unsigned short* hp = (unsigned short*)&hv;
        unsigned short* lp = (unsigned short*)&lv;
        unsigned short* l2p = (unsigned short*)&l2v;
#pragma unroll
        for (int j = 0; j < 4; ++j) {
            float v = T[kk + j][nn];
            unsigned short h = f2bf(v);
            hp[j] = h;
            if (P == 3) {
                float r1 = v - bf2f(h);
                unsigned short l = f2bf(r1);
                lp[j] = l;
                l2p[j] = f2bf(r1 - bf2f(l));
            }
        }
        unsigned short* dp = dst + (size_t)(n0 + nn) * K + k0 + kk;
        *(ushort4*)dp = hv;
        if (P == 3) {
            *(ushort4*)(dp + NK) = lv;
            *(ushort4*)(dp + 2 * NK) = l2v;
        }
    }
}

// ---------- GEMM: C = A * B via bf16 MFMA, 128x128 tile, BK=32, expert-batched in z ----------
// TERMS=6: 3-term split both sides (fp32-grade). TERMS=1: plain bf16.
// AMODE: 0 direct (+e*astride); 1 compact base+row; 2 gather flat[base+row].
// CMODE: 0 direct (+e*cstride); 1 compact masked; 2 scatter flat[base+row] masked.
// BPRE: 0 = B f32 [K][N], in-loop split+transpose; 1 = B pre-split bf16 planes [P][N][K].
// A16:  0 = A f32, in-loop split; 1 = A bf16 [M][K], pure copy staging (TERMS must be 1).
// C16:  0 = C f32; 1 = C bf16.
template<int TERMS, int AMODE, int CMODE, int NW, int BPRE, int A16, int C16>
__global__ __launch_bounds__(256, 2)
void gemm_kernel(const void* __restrict__ Av,
                 const void* __restrict__ B0, const void* __restrict__ B1, const void* __restrict__ B2,
                 void* __restrict__ C0, void* __restrict__ C1, void* __restrict__ C2,
                 int M, int N, int K,
                 size_t astride, size_t bstride, size_t cstride,
                 const int* __restrict__ OFF, const int* __restrict__ flat)
{
    const int z = blockIdx.z;
    const int e = z / NW, w = z - e * NW;
    int base = 0, cnt = M;
    if (AMODE == 1 || AMODE == 2 || CMODE == 1 || CMODE == 2) {
        base = OFF[e * 8];
        cnt  = OFF[e * 8 + 8] - base;
        if ((int)blockIdx.x * 128 >= cnt) return;
    }
    const void* Bsel = (NW == 3 ? (w == 0 ? B0 : w == 1 ? B1 : B2) : B0);
    void*       Csel = (NW == 3 ? (w == 0 ? C0 : w == 1 ? C1 : C2) : C0);
    const float*          Af = (const float*)Av + (size_t)e * astride;
    const unsigned short* As = (const unsigned short*)Av;
    const float*          Bf = (const float*)Bsel + (size_t)e * bstride;
    const unsigned short* Bp = (const unsigned short*)Bsel + (size_t)e * bstride;
    float*          Cf = (float*)Csel + (size_t)e * cstride;
    unsigned short* Cs = (unsigned short*)Csel + (size_t)e * cstride;
    const size_t NKb = (size_t)N * K;

    constexpr int NPL = (TERMS == 6) ? 3 : 1;
    __shared__ unsigned short Asm[NPL][128 * 40];   // padded stride 40
    __shared__ unsigned short Bsm[NPL][128 * 40];   // Bsm[n][k]

    const int tid   = threadIdx.x;
    const int lane  = tid & 63;
    const int wid   = tid >> 6;
    const int wm    = wid & 1, wn = wid >> 1;
    const int mlane = lane & 15, quad = lane >> 4;
    const int row0  = blockIdx.x * 128;
    const int col0  = blockIdx.y * 128;

    f32x4 acc[4][4];
#pragma unroll
    for (int i = 0; i < 4; ++i)
#pragma unroll
        for (int j = 0; j < 4; ++j)
#pragma unroll
            for (int r = 0; r < 4; ++r) acc[i][j][r] = 0.f;

    for (int k0 = 0; k0 < K; k0 += 32) {
        // ---- stage A ----
        if (A16 == 0) {
#pragma unroll
            for (int i = 0; i < 4; ++i) {
                int idx = tid + (i << 8);
                int r = idx >> 3;
                int c = (idx & 7) << 2;
                int lr = row0 + r;
                if (AMODE != 0) lr = min(lr, cnt - 1);
                size_t arow = (AMODE == 2) ? (size_t)flat[base + lr]
                            : (AMODE == 1) ? (size_t)(base + lr) : (size_t)lr;
                const float4 a = *(const float4*)(Af + arow * K + k0 + c);
                float av[4] = {a.x, a.y, a.z, a.w};
                ushort4 hv, lv, l2v;
                unsigned short* hp  = (unsigned short*)&hv;
                unsigned short* lp  = (unsigned short*)&lv;
                unsigned short* l2p = (unsigned short*)&l2v;
#pragma unroll
                for (int j = 0; j < 4; ++j) {
                    unsigned short h = f2bf(av[j]);
                    hp[j] = h;
                    if (TERMS == 6) {
                        float r1 = av[j] - bf2f(h);
                        unsigned short l = f2bf(r1);
                        lp[j]  = l;
                        l2p[j] = f2bf(r1 - bf2f(l));
                    }
                }
                *(ushort4*)&Asm[0][r * 40 + c] = hv;
                if (TERMS == 6) {
                    *(ushort4*)&Asm[1][r * 40 + c] = lv;
                    *(ushort4*)&Asm[2][r * 40 + c] = l2v;
                }
            }
        } else {
#pragma unroll
            for (int j = 0; j < 2; ++j) {
                int c = tid * 2 + j;                 // 512 chunks of 8 shorts
                int r = c >> 2, q8 = (c & 3) << 3;
                int lr = row0 + r;
                if (AMODE != 0) lr = min(lr, cnt - 1);
                size_t arow = (AMODE == 2) ? (size_t)flat[base + lr]
                            : (AMODE == 1) ? (size_t)(base + lr) : (size_t)lr;
                *(uint4*)&Asm[0][r * 40 + q8] = *(const uint4*)(As + arow * K + k0 + q8);
            }
        }
        // ---- stage B ----
        if (BPRE == 0) {
#pragma unroll
            for (int i = 0; i < 2; ++i) {
                int idx = tid + (i << 8);
                int kk = idx >> 4;
                int n8 = (idx & 15) << 3;
                const float* bp = Bf + (size_t)(k0 + kk) * N + col0 + n8;
                const float4 b0 = *(const float4*)bp;
                const float4 b1 = *(const float4*)(bp + 4);
                float bv[8] = {b0.x, b0.y, b0.z, b0.w, b1.x, b1.y, b1.z, b1.w};
#pragma unroll
                for (int j = 0; j < 8; ++j) {
                    unsigned short h = f2bf(bv[j]);
                    Bsm[0][(n8 + j) * 40 + kk] = h;
                    if (TERMS == 6) {
                        float r1 = bv[j] - bf2f(h);
                        unsigned short l = f2bf(r1);
                        Bsm[1][(n8 + j) * 40 + kk] = l;
                        Bsm[2][(n8 + j) * 40 + kk] = f2bf(r1 - bf2f(l));
                    }
                }
            }
        } else {
#pragma unroll
            for (int p = 0; p < NPL; ++p)
#pragma unroll
                for (int j = 0; j < 2; ++j) {
                    int c = tid * 2 + j;
                    int r = c >> 2, q8 = (c & 3) << 3;
                    *(uint4*)&Bsm[p][r * 40 + q8] =
                        *(const uint4*)(Bp + (size_t)p * NKb + (size_t)(col0 + r) * K + k0 + q8);
                }
        }
        __syncthreads();

        bf16_8 fa[3][4], fb[3][4];
#pragma unroll
        for (int t = 0; t < 4; ++t) {
            int ar = (wm * 64 + t * 16 + mlane) * 40 + quad * 8;
            int br = (wn * 64 + t * 16 + mlane) * 40 + quad * 8;
            fa[0][t] = *(const bf16_8*)&Asm[0][ar];
            fb[0][t] = *(const bf16_8*)&Bsm[0][br];
            if (TERMS == 6) {
                fa[1][t] = *(const bf16_8*)&Asm[1][ar];
                fa[2][t] = *(const bf16_8*)&Asm[2][ar];
                fb[1][t] = *(const bf16_8*)&Bsm[1][br];
                fb[2][t] = *(const bf16_8*)&Bsm[2][br];
            }
        }
        const int ta[6] = {0, 0, 1, 0, 1, 2};
        const int tb[6] = {0, 1, 0, 2, 1, 0};
#pragma unroll
        for (int s = 0; s < TERMS; ++s)
#pragma unroll
            for (int mt = 0; mt < 4; ++mt)
#pragma unroll
                for (int nt = 0; nt < 4; ++nt)
                    acc[mt][nt] = __builtin_amdgcn_mfma_f32_16x16x32_bf16(
                        fa[ta[s]][mt], fb[tb[s]][nt], acc[mt][nt], 0, 0, 0);
        __syncthreads();
    }

    // ---- epilogue: C/D layout col=lane&15, row=quad*4+reg ----
#pragma unroll
    for (int mt = 0; mt < 4; ++mt)
#pragma unroll
        for (int nt = 0; nt < 4; ++nt) {
            int c = col0 + wn * 64 + nt * 16 + mlane;
#pragma unroll
            for (int j = 0; j < 4; ++j) {
                int lr = row0 + wm * 64 + mt * 16 + quad * 4 + j;
                if ((CMODE == 1 || CMODE == 2) && lr >= cnt) continue;
                size_t crow = (CMODE == 2) ? (size_t)flat[base + lr]
                            : (CMODE == 1) ? (size_t)(base + lr) : (size_t)lr;
                if (C16) Cs[crow * N + c] = f2bf(acc[mt][nt][j]);
                else     Cf[crow * N + c] = acc[mt][nt][j];
            }
        }
}

// ---------- fp32 flash attention (shared block), d-sliced ----------
__global__ __launch_bounds__(256, 4)
void attn_kernel(const float* __restrict__ Q, const float* __restrict__ Km,
                 const float* __restrict__ V, float* __restrict__ O)
{
    __shared__ float ks[64][68];
    __shared__ float vs[64][68];

    const int tid = threadIdx.x;
    const int qt  = blockIdx.x & 15;
    const int h   = (blockIdx.x >> 4) & 7;
    const int b   = blockIdx.x >> 7;
    const size_t rowbase = (size_t)b * 1024;
    const int colbase = h * 64;
    const int q = tid >> 2, sub = tid & 3;
    const int ds = sub << 4;
    const size_t qrow = (rowbase + qt * 64 + q) * 512 + colbase;

    float4 qreg[4];
#pragma unroll
    for (int i = 0; i < 4; ++i) qreg[i] = *(const float4*)(Q + qrow + ds + i * 4);

    float4 oacc[4];
#pragma unroll
    for (int i = 0; i < 4; ++i) { oacc[i].x = oacc[i].y = oacc[i].z = oacc[i].w = 0.f; }
    float m = -1e30f, l = 0.f;

    for (int tt = 0; tt < 16; ++tt) {
        __syncthreads();
#pragma unroll
        for (int i = 0; i < 4; ++i) {
            int idx = tid + (i << 8);
            int r = idx >> 4, c = (idx & 15) << 2;
            const size_t g = (rowbase + tt * 64 + r) * 512 + colbase + c;
            *(float4*)&ks[r][c] = *(const float4*)(Km + g);
            *(float4*)&vs[r][c] = *(const float4*)(V + g);
        }
        __syncthreads();

#pragma unroll
        for (int c = 0; c < 4; ++c) {
            float s[16];
#pragma unroll
            for (int jj = 0; jj < 16; ++jj) {
                const int j = (c << 4) + jj;
                const float* kp = &ks[j][ds];
                float4 k0 = *(const float4*)kp;
                float4 k1 = *(const float4*)(kp + 4);
                float4 k2 = *(const float4*)(kp + 8);
                float4 k3 = *(const float4*)(kp + 12);
                float t = qreg[0].x * k0.x + qreg[0].y * k0.y + qreg[0].z * k0.z + qreg[0].w * k0.w
                        + qreg[1].x * k1.x + qreg[1].y * k1.y + qreg[1].z * k1.z + qreg[1].w * k1.w
                        + qreg[2].x * k2.x + qreg[2].y * k2.y + qreg[2].z * k2.z + qreg[2].w * k2.w
                        + qreg[3].x * k3.x + qreg[3].y * k3.y + qreg[3].z * k3.z + qreg[3].w * k3.w;
                t += __shfl_xor(t, 1);
                t += __shfl_xor(t, 2);
                s[jj] = t * 0.125f;
            }
            float mloc = s[0];
#pragma unroll
            for (int jj = 1; jj < 16; ++jj) mloc = fmaxf(mloc, s[jj]);
            float mnew = fmaxf(m, mloc);
            float alpha = __expf(m - mnew);
            float lt = 0.f;
#pragma unroll
            for (int jj = 0; jj < 16; ++jj) { s[jj] = __expf(s[jj] - mnew); lt += s[jj]; }
            l = l * alpha + lt;
#pragma unroll
            for (int i = 0; i < 4; ++i) {
                oacc[i].x *= alpha; oacc[i].y *= alpha;
                oacc[i].z *= alpha; oacc[i].w *= alpha;
            }
#pragma unroll
            for (int jj = 0; jj < 16; ++jj) {
                const float pj = s[jj];
                const float* vp = &vs[(c << 4) + jj][ds];
#pragma unroll
                for (int i = 0; i < 4; ++i) {
                    float4 v = *(const float4*)(vp + i * 4);
                    oacc[i].x += pj * v.x; oacc[i].y += pj * v.y;
                    oacc[i].z += pj * v.z; oacc[i].w += pj * v.w;
                }
            }
            m = mnew;
        }
    }

    const float inv = 1.f / l;
#pragma unroll
    for (int i = 0; i < 4; ++i) {
        float4 o;
        o.x = oacc[i].x * inv; o.y = oacc[i].y * inv;
        o.z = oacc[i].z * inv; o.w = oacc[i].w * inv;
        *(float4*)(O + qrow + ds + i * 4) = o;
    }
}

// ---------- compacted expert attention, zero-key correction, bf16 out = attn - meanV ----------
__global__ __launch_bounds__(256, 4)
void attn_compact_kernel(const float* __restrict__ Qc, const float* __restrict__ Kc,
                         const float* __restrict__ Vc, const float* __restrict__ meanV,
                         unsigned short* __restrict__ AOc, const int* __restrict__ OFF)
{
    const int qt = blockIdx.x & 15;
    const int h  = (blockIdx.x >> 4) & 7;
    const int e  = (blockIdx.x >> 7) & 3;
    const int b  = blockIdx.x >> 9;
    const int base = OFF[e * 8 + b];
    const int c    = OFF[e * 8 + b + 1] - base;
    if (qt * 64 >= c) return;
    const int nq = min(64, c - qt * 64);

    __shared__ float ks[64][68];
    __shared__ float vs[64][68];

    const int tid = threadIdx.x;
    const int q = tid >> 2, sub = tid & 3;
    const int ds = sub << 4;
    const int colbase = h * 64;
    const size_t qrow = (size_t)(base + qt * 64 + min(q, nq - 1)) * 512 + colbase;

    float4 qreg[4];
#pragma unroll
    for (int i = 0; i < 4; ++i) qreg[i] = *(const float4*)(Qc + qrow + ds + i * 4);

    float4 oacc[4];
#pragma unroll
    for (int i = 0; i < 4; ++i) { oacc[i].x = oacc[i].y = oacc[i].z = oacc[i].w = 0.f; }
    float m = -1e30f, l = 0.f;

    for (int kt = 0; kt * 64 < c; ++kt) {
        const int cmax = c - kt * 64 - 1;
        __syncthreads();
#pragma unroll
        for (int i = 0; i < 4; ++i) {
            int idx = tid + (i << 8);
            int r = idx >> 4, cc = (idx & 15) << 2;
            const size_t g = (size_t)(base + kt * 64 + min(r, cmax)) * 512 + colbase + cc;
            *(float4*)&ks[r][cc] = *(const float4*)(Kc + g);
            *(float4*)&vs[r][cc] = *(const float4*)(Vc + g);
        }
        __syncthreads();

#pragma unroll
        for (int ch = 0; ch < 4; ++ch) {
            float s[16];
#pragma unroll
            for (int jj = 0; jj < 16; ++jj) {
                const int j = (ch << 4) + jj;
                const float* kp = &ks[j][ds];
                float4 k0 = *(const float4*)kp;
                float4 k1 = *(const float4*)(kp + 4);
                float4 k2 = *(const float4*)(kp + 8);
                float4 k3 = *(const float4*)(kp + 12);
                float t = qreg[0].x * k0.x + qreg[0].y * k0.y + qreg[0].z * k0.z + qreg[0].w * k0.w
                        + qreg[1].x * k1.x + qreg[1].y * k1.y + qreg[1].z * k1.z + qreg[1].w * k1.w
                        + qreg[2].x * k2.x + qreg[2].y * k2.y + qreg[2].z * k2.z + qreg[2].w * k2.w
                        + qreg[3].x * k3.x + qreg[3].y * k3.y + qreg[3].z * k3.z + qreg[3].w * k3.w;
                t += __shfl_xor(t, 1);
                t += __shfl_xor(t, 2);
                s[jj] = (kt * 64 + j < c) ? t * 0.125f : -1e30f;
            }
            float mloc = s[0];
#pragma unroll
            for (int jj = 1; jj < 16; ++jj) mloc = fmaxf(mloc, s[jj]);
            float mnew = fmaxf(m, mloc);
            float alpha = __expf(m - mnew);
            float lt = 0.f;
#pragma unroll
            for (int jj = 0; jj < 16; ++jj) { s[jj] = __expf(s[jj] - mnew); lt += s[jj]; }
            l = l * alpha + lt;
#pragma unroll
            for (int i = 0; i < 4; ++i) {
                oacc[i].x *= alpha; oacc[i].y *= alpha;
                oacc[i].z *= alpha; oacc[i].w *= alpha;
            }
#pragma unroll
            for (int jj = 0; jj < 16; ++jj) {
                const float pj = s[jj];
                const float* vp = &vs[(ch << 4) + jj][ds];
#pragma unroll
                for (int i = 0; i < 4; ++i) {
                    float4 v = *(const float4*)(vp + i * 4);
                    oacc[i].x += pj * v.x; oacc[i].y += pj * v.y;
                    oacc[i].z += pj * v.z; oacc[i].w += pj * v.w;
                }
            }
            m = mnew;
        }
    }

    float mfin = (c < 1024) ? fmaxf(m, 0.f) : m;
    float alphaf = __expf(m - mfin);
    l = l * alphaf + (float)(1024 - c) * __expf(-mfin);
#pragma unroll
    for (int i = 0; i < 4; ++i) {
        oacc[i].x *= alphaf; oacc[i].y *= alphaf;
        oacc[i].z *= alphaf; oacc[i].w *= alphaf;
    }

    if (q < nq) {
        const float inv = 1.f / l;
        const size_t orow = (size_t)(base + qt * 64 + q) * 512 + colbase;
        const float* mv = meanV + e * 65536 + b * 512 + colbase + ds;
#pragma unroll
        for (int i = 0; i < 4; ++i) {
            float4 mvv = *(const float4*)(mv + i * 4);
            ushort4 o;
            o.x = f2bf(oacc[i].x * inv - mvv.x); o.y = f2bf(oacc[i].y * inv - mvv.y);
            o.z = f2bf(oacc[i].z * inv - mvv.z); o.w = f2bf(oacc[i].w * inv - mvv.w);
            *(ushort4*)&AOc[orow + ds + i * 4] = o;
        }
    }
}

// ---------- meanV per (b,e,h): M32[e][b][h*64+d] = sum(Vc rows)/1024 ----------
__global__ void sumv_kernel(const float* __restrict__ Vc, const int* __restrict__ OFF,
                            float* __restrict__ M32)
{
    const int h = blockIdx.x & 7, e = (blockIdx.x >> 3) & 3, b = blockIdx.x >> 5;
    const int base = OFF[e * 8 + b], c = OFF[e * 8 + b + 1] - base;
    const int tid = threadIdx.x;
    const int d = tid & 63, g = tid >> 6;
    float s = 0.f;
    for (int r = g; r < c; r += 4) s += Vc[(size_t)(base + r) * 512 + h * 64 + d];
    __shared__ float red[256];
    red[tid] = s;
    __syncthreads();
    if (g == 0)
        M32[e * 65536 + b * 512 + h * 64 + d] =
            (red[d] + red[64 + d] + red[128 + d] + red[192 + d]) * (1.f / 1024.f);
}

// ---------- embedding gather ----------
__global__ void gather_kernel(const int* __restrict__ tokens,
                              const float* __restrict__ emb,
                              float* __restrict__ X)
{
    const int t = blockIdx.x;
    const int tok = tokens[t];
    const float4* src = (const float4*)(emb + (size_t)tok * 512);
    float4* dst = (float4*)(X + (size_t)t * 512);
    dst[threadIdx.x] = src[threadIdx.x];
}

// ---------- gate + argmax ----------
__global__ __launch_bounds__(256)
void gate_kernel(const float* __restrict__ H, const float* __restrict__ Wg,
                 int* __restrict__ idx)
{
    const int t = blockIdx.x * 4 + (threadIdx.x >> 6);
    const int lane = threadIdx.x & 63;
    float a0 = 0, a1 = 0, a2 = 0, a3 = 0;
#pragma unroll
    for (int i = 0; i < 8; ++i) {
        int d = i * 64 + lane;
        float hv = H[(size_t)t * 512 + d];
        a0 += hv * Wg[d * 4 + 0];
        a1 += hv * Wg[d * 4 + 1];
        a2 += hv * Wg[d * 4 + 2];
        a3 += hv * Wg[d * 4 + 3];
    }
#pragma unroll
    for (int off = 32; off > 0; off >>= 1) {
        a0 += __shfl_down(a0, off);
        a1 += __shfl_down(a1, off);
        a2 += __shfl_down(a2, off);
        a3 += __shfl_down(a3, off);
    }
    if (lane == 0) {
        int best = 0; float bv = a0;
        if (a1 > bv) { bv = a1; best = 1; }
        if (a2 > bv) { bv = a2; best = 2; }
        if (a3 > bv) { bv = a3; best = 3; }
        idx[t] = best;
    }
}

// ---------- compaction: count / offsets / fill ----------
__global__ void count_kernel(const int* __restrict__ idx, int* __restrict__ cnt)
{
    const int t = blockIdx.x * 256 + threadIdx.x;
    atomicAdd(&cnt[idx[t] * 8 + (t >> 10)], 1);
}
__global__ void offsets_kernel(const int* __restrict__ cnt, int* __restrict__ OFF,
                               int* __restrict__ cursor)
{
    if (threadIdx.x == 0) {
        int a = 0;
        for (int i = 0; i < 32; ++i) { OFF[i] = a; cursor[i] = a; a += cnt[i]; }
        OFF[32] = a;
    }
}
__global__ void fill_kernel(const int* __restrict__ idx, int* __restrict__ cursor,
                            int* __restrict__ flat)
{
    const int t = blockIdx.x * 256 + threadIdx.x;
    const int p = atomicAdd(&cursor[idx[t] * 8 + (t >> 10)], 1);
    flat[p] = t;
}

// ---------- SB[b] = sum_e G2[e][b][:] . Wout ----------
__global__ void sb_kernel(const float* __restrict__ G2, const float* __restrict__ Wout,
                          float* __restrict__ SB)
{
    const int tid = threadIdx.x;
    const int pair = tid >> 3, t8 = tid & 7;
    const int e = pair >> 3, b = pair & 7;
    float s = 0.f;
    for (int d = t8; d < 512; d += 8) s += G2[e * 65536 + b * 512 + d] * Wout[d];
    __shared__ float red[256];
    __shared__ float red2[32];
    red[tid] = s;
    __syncthreads();
    if (tid < 32) {
        float t = 0.f;
#pragma unroll
        for (int k = 0; k < 8; ++k) t += red[tid * 8 + k];
        red2[tid] = t;
    }
    __syncthreads();
    if (tid < 8)
        SB[tid] = red2[tid] + red2[8 + tid] + red2[16 + tid] + red2[24 + tid];
}

// ---------- head: out[t] = OA[t,:].Wout + SB[b(t)] ----------
__global__ __launch_bounds__(256)
void wout_kernel(const float* __restrict__ OUT, const float* __restrict__ Wout,
                 const float* __restrict__ SB, float* __restrict__ out)
{
    const int t = blockIdx.x * 4 + (threadIdx.x >> 6);
    const int lane = threadIdx.x & 63;
    float s = 0.f;
#pragma unroll
    for (int i = 0; i < 8; ++i) {
        int d = i * 64 + lane;
        s += OUT[(size_t)t * 512 + d] * Wout[d];
    }
#pragma unroll
    for (int off = 32; off > 0; off >>= 1) s += __shfl_down(s, off);
    if (lane == 0) out[t] = s + SB[t >> 10];
}

// ---------- launch ----------
extern "C" void kernel_launch(void* const* d_in, const int* in_sizes, int n_in,
                              void* d_out, int out_size, void* d_ws, size_t ws_size,
                              hipStream_t stream)
{
    const int*   tokens = (const int*)d_in[0];
    const float* emb  = (const float*)d_in[1];
    const float* Wq   = (const float*)d_in[2];
    const float* Wk   = (const float*)d_in[3];
    const float* Wv   = (const float*)d_in[4];
    const float* Wo   = (const float*)d_in[5];
    const float* W1   = (const float*)d_in[6];
    const float* W2   = (const float*)d_in[7];
    const float* Wg   = (const float*)d_in[8];
    const float* eWq  = (const float*)d_in[9];
    const float* eWk  = (const float*)d_in[10];
    const float* eWv  = (const float*)d_in[11];
    const float* eWo  = (const float*)d_in[12];
    const float* eW1  = (const float*)d_in[13];
    const float* eW2  = (const float*)d_in[14];
    const float* Wout = (const float*)d_in[15];
    float* outp = (float*)d_out;

    float* WS = (float*)d_ws;
    const size_t SZ = (size_t)8192 * 512;
    float* P0 = WS, *P1 = WS + SZ, *P2 = WS + 2 * SZ, *P3 = WS + 3 * SZ, *P4 = WS + 4 * SZ;

    // weight planes (shorts) after the 5 f32 planes
    unsigned short* SP   = (unsigned short*)(WS + 5 * SZ);
    unsigned short* sW1p = SP;                      // [3][2048][512]
    unsigned short* sW2p = SP + 3145728;            // [3][512][2048]
    unsigned short* xWq  = SP + 6291456;            // [4][512][512]
    unsigned short* xWk  = xWq + 1048576;
    unsigned short* xWv  = xWk + 1048576;
    unsigned short* xWo  = xWv + 1048576;
    unsigned short* xW1  = xWo + 1048576;           // [4][2048][512]
    unsigned short* xW2  = xW1 + 4194304;           // [4][512][2048]

    float* MBase = WS + 5 * SZ + 9437184;           // misc region
    int* IDX    = (int*)MBase;
    int* cnt    = (int*)(MBase + 8192);
    int* OFFp   = (int*)(MBase + 8224);
    int* cursor = (int*)(MBase + 8264);
    int* flat   = (int*)(MBase + 8304);
    float* M32  = MBase + 16640;                    // [4][128][512]
    float* G0   = M32 + 262144;
    float* G2   = G0 + 262144;
    float* SB   = G2 + 262144;

    // shared-phase aliases
    float* X = P4, *Qb = P0, *Kb = P1, *Vb = P2, *AO = P3, *T0 = P4, *T1 = P0, *Hb = P4;
    // expert-phase aliases
    float* Qc = P0, *Kc = P1, *Vc = P2;
    unsigned short* AOc = (unsigned short*)P3;              // [8192][512] bf16 (P3a)
    unsigned short* T0c = (unsigned short*)(P3 + 2097152);  // [8192][512] bf16 (P3b)
    unsigned short* T1c = (unsigned short*)P0;              // [8192][2048] bf16 (P0..P1)
    float* G1 = P2;                                         // [4][128][2048]
    float* OA = P3;

    const int M = 8192, D = 512, FF = 2048;
    const size_t sDD = (size_t)D * D, sDF = (size_t)D * FF;
    const float* NUL = nullptr;
    float* NULm = nullptr;

    // ---- weight prep: transpose+split once per call (~20 us) ----
    wsplit_kernel<3><<<dim3(32, 8, 1),  256, 0, stream>>>(W1, NUL, NUL, NUL, sW1p, 0, 0, 0, D, FF, 1, 0, 0);
    wsplit_kernel<3><<<dim3(8, 32, 1),  256, 0, stream>>>(W2, NUL, NUL, NUL, sW2p, 0, 0, 0, FF, D, 1, 0, 0);
    wsplit_kernel<1><<<dim3(8, 8, 16),  256, 0, stream>>>(eWq, eWk, eWv, eWo, xWq, xWk, xWv, xWo, D, D, 4, sDD, 262144);
    wsplit_kernel<1><<<dim3(32, 8, 4),  256, 0, stream>>>(eW1, NUL, NUL, NUL, xW1, 0, 0, 0, D, FF, 4, sDF, 1048576);
    wsplit_kernel<1><<<dim3(8, 32, 4),  256, 0, stream>>>(eW2, NUL, NUL, NUL, xW2, 0, 0, 0, FF, D, 4, sDF, 1048576);

    // ---- shared block (argmax-safe, 6-term split) ----
    gather_kernel<<<8192, 128, 0, stream>>>(tokens, emb, X);
    gemm_kernel<6, 0, 0, 3, 0, 0, 0><<<dim3(64, 4, 3), 256, 0, stream>>>(
        X, Wq, Wk, Wv, Qb, Kb, Vb, M, D, D, 0, 0, 0, nullptr, nullptr);
    attn_kernel<<<1024, 256, 0, stream>>>(Qb, Kb, Vb, AO);
    gemm_kernel<6, 0, 0, 1, 0, 0, 0><<<dim3(64, 4, 1), 256, 0, stream>>>(
        AO, Wo, NUL, NUL, T0, NULm, NULm, M, D, D, 0, 0, 0, nullptr, nullptr);
    gemm_kernel<6, 0, 0, 1, 1, 0, 0><<<dim3(64, 16, 1), 256, 0, stream>>>(
        T0, sW1p, NUL, NUL, T1, NULm, NULm, M, FF, D, 0, 0, 0, nullptr, nullptr);
    gemm_kernel<6, 0, 0, 1, 1, 0, 0><<<dim3(64, 4, 1), 256, 0, stream>>>(
        T1, sW2p, NUL, NUL, Hb, NULm, NULm, M, D, FF, 0, 0, 0, nullptr, nullptr);
    gate_kernel<<<2048, 256, 0, stream>>>(Hb, Wg, IDX);

    // ---- compaction ----
    hipMemsetAsync(cnt, 0, 32 * sizeof(int), stream);
    hipMemsetAsync(M32, 0, 4 * 128 * 512 * sizeof(float), stream);
    count_kernel<<<32, 256, 0, stream>>>(IDX, cnt);
    offsets_kernel<<<1, 64, 0, stream>>>(cnt, OFFp, cursor);
    fill_kernel<<<32, 256, 0, stream>>>(IDX, cursor, flat);

    // ---- expert QKV (gather A=Hb f32, pre-split B planes, C f32 compact) ----
    gemm_kernel<1, 2, 1, 3, 1, 0, 0><<<dim3(64, 4, 12), 256, 0, stream>>>(
        Hb, xWq, xWk, xWv, Qc, Kc, Vc, M, D, D, 0, 262144, 0, OFFp, flat);
    sumv_kernel<<<256, 256, 0, stream>>>(Vc, OFFp, M32);
    attn_compact_kernel<<<4096, 256, 0, stream>>>(Qc, Kc, Vc, M32, AOc, OFFp);

    // ---- expert FFN chain (A bf16 direct, B planes, C bf16) ----
    gemm_kernel<1, 1, 1, 1, 1, 1, 1><<<dim3(64, 4, 4), 256, 0, stream>>>(
        AOc, xWo, NUL, NUL, T0c, NULm, NULm, M, D, D, 0, 262144, 0, OFFp, flat);
    gemm_kernel<1, 1, 1, 1, 1, 1, 1><<<dim3(64, 16, 4), 256, 0, stream>>>(
        T0c, xW1, NUL, NUL, T1c, NULm, NULm, M, FF, D, 0, 1048576, 0, OFFp, flat);

    // ---- meanV path (tiny, legacy f32-B kernel) ----
    gemm_kernel<1, 0, 0, 1, 0, 0, 0><<<dim3(1, 4, 4), 256, 0, stream>>>(
        M32, eWo, NUL, NUL, G0, NULm, NULm, 128, D, D, 65536, sDD, 65536, nullptr, nullptr);
    gemm_kernel<1, 0, 0, 1, 0, 0, 0><<<dim3(1, 16, 4), 256, 0, stream>>>(
        G0, eW1, NUL, NUL, G1, NULm, NULm, 128, FF, D, 65536, sDF, 262144, nullptr, nullptr);
    gemm_kernel<1, 0, 0, 1, 0, 0, 0><<<dim3(1, 4, 4), 256, 0, stream>>>(
        G1, eW2, NUL, NUL, G2, NULm, NULm, 128, D, FF, 262144, sDF, 65536, nullptr, nullptr);

    // ---- expert W2: A=T1c bf16, scatter f32 into OA ----
    gemm_kernel<1, 1, 2, 1, 1, 1, 0><<<dim3(64, 4, 4), 256, 0, stream>>>(
        T1c, xW2, NUL, NUL, OA, NULm, NULm, M, D, FF, 0, 1048576, 0, OFFp, flat);

    sb_kernel<<<1, 256, 0, stream>>>(G2, Wout, SB);
    wout_kernel<<<2048, 256, 0, stream>>>(OA, Wout, SB, outp);
}